// Round 4
// baseline (660.829 us; speedup 1.0000x reference)
//
#include <hip/hip_runtime.h>

#define N_GRID 262144
#define BSZ 128
#define NNZ_TOT 1835008
#define ROWS_PER_BLOCK 32
#define NBLK_FUSED (N_GRID / ROWS_PER_BLOCK)   // 8192
#define PAIR_CAP (NNZ_TOT + 8 * N_GRID)        // min-8 padded worst case = 3932160

#define TR_BLOCKS ((N_GRID / 64) * (BSZ / 64)) // 8192 transpose blocks
#define HIST_BLOCKS (NNZ_TOT / 1024)           // 1792 hist blocks
#define SCAT_BLOCKS (NNZ_TOT / 1024)           // 1792 scatter blocks
#define PADZ_BLOCKS (N_GRID / 1024)            // 256 pad-zero blocks (4 rows/thread)

typedef float v4f __attribute__((ext_vector_type(4)));
typedef int   v2i __attribute__((ext_vector_type(2)));

// ws layout (8B-aligned):
//   ypT     : N*BSZ f32          = 134 MB  (y_pred transposed)
//   acc     : 5*128 doubles      = 5120 B  (s1, t2, s2, s3, s4)
//   counts  : N ints             = 1 MB
//   ptr     : N+2 ints           = 1 MB    (padded CSR row pointers, every row >= 8 slots)
//   bsums   : 512 ints           = 2 KB
//   pairs   : PAIR_CAP int2      = 31.5 MB (col, bitcast val), row-sorted, pad slots zeroed in K4
//   partial : NBLK_FUSED*640 f32 = 21 MB   (per-block partial sums)
//   rank    : overlays partial   = 7.3 MB  (per-nonzero rank within row; dead before fused)

// ---- K1: [blocks 0..TR) transpose y_pred -> ypT  ||  [TR..TR+HIST) histogram+rank ----
__global__ __launch_bounds__(256) void phase1_kernel(const float* __restrict__ yp,
                                                     float* __restrict__ ypT,
                                                     const int* __restrict__ rows,
                                                     int* __restrict__ counts,
                                                     int* __restrict__ rank) {
    if (blockIdx.x < TR_BLOCKS) {
        __shared__ float tile[64 * 65];
        int n0 = (blockIdx.x >> 1) * 64;   // 4096 n-tiles
        int b0 = (blockIdx.x & 1) * 64;    // 2 b-tiles
        int tx = threadIdx.x & 15;   // 0..15 -> 4 floats each
        int ty = threadIdx.x >> 4;   // 0..15
#pragma unroll
        for (int jj = 0; jj < 4; ++jj) {
            int b = b0 + ty + jj * 16;
            v4f v = __builtin_nontemporal_load((const v4f*)&yp[(size_t)b * N_GRID + n0 + 4 * tx]);
            tile[(4 * tx + 0) * 65 + ty + jj * 16] = v.x;
            tile[(4 * tx + 1) * 65 + ty + jj * 16] = v.y;
            tile[(4 * tx + 2) * 65 + ty + jj * 16] = v.z;
            tile[(4 * tx + 3) * 65 + ty + jj * 16] = v.w;
        }
        __syncthreads();
#pragma unroll
        for (int jj = 0; jj < 4; ++jj) {
            int nl = ty + jj * 16;
            v4f v;
            v.x = tile[nl * 65 + 4 * tx + 0];
            v.y = tile[nl * 65 + 4 * tx + 1];
            v.z = tile[nl * 65 + 4 * tx + 2];
            v.w = tile[nl * 65 + 4 * tx + 3];
            *(v4f*)&ypT[(size_t)(n0 + nl) * BSZ + b0 + 4 * tx] = v;  // normal: want L3-resident
        }
    } else {
        int bid = blockIdx.x - TR_BLOCKS;
        int k0 = bid * 1024 + threadIdx.x;
        int kend = bid * 1024 + 1024;
#pragma unroll
        for (int k = k0; k < kend; k += 256) {
            int r = __builtin_nontemporal_load(&rows[k]);
            int rk = atomicAdd(&counts[r], 1);
            __builtin_nontemporal_store(rk, &rank[k]);
        }
    }
}

// ---- K2a: per-block exclusive scan of PADDED counts (512 elems/block) ----
__global__ __launch_bounds__(512) void scan1_kernel(const int* __restrict__ counts,
                                                    int* __restrict__ ptr,
                                                    int* __restrict__ bsums) {
    __shared__ int sdata[512];
    int i = blockIdx.x * 512 + threadIdx.x;
    int x = (counts[i] + 7) & ~7;   // pad each row to a multiple of 8
    if (x < 8) x = 8;               // min 8 slots: makes first chunk unconditional in K5
    sdata[threadIdx.x] = x;
    __syncthreads();
    for (int off = 1; off < 512; off <<= 1) {
        int v = 0;
        if ((int)threadIdx.x >= off) v = sdata[threadIdx.x - off];
        __syncthreads();
        sdata[threadIdx.x] += v;
        __syncthreads();
    }
    ptr[i] = sdata[threadIdx.x] - x;
    if (threadIdx.x == 511) bsums[blockIdx.x] = sdata[511];
}

// ---- K2b: exclusive scan of 512 block sums; grand total -> ptr[N] ----
__global__ __launch_bounds__(512) void scan2_kernel(int* __restrict__ bsums,
                                                    int* __restrict__ ptr) {
    __shared__ int sdata[512];
    int x = bsums[threadIdx.x];
    sdata[threadIdx.x] = x;
    __syncthreads();
    for (int off = 1; off < 512; off <<= 1) {
        int v = 0;
        if ((int)threadIdx.x >= off) v = sdata[threadIdx.x - off];
        __syncthreads();
        sdata[threadIdx.x] += v;
        __syncthreads();
    }
    bsums[threadIdx.x] = sdata[threadIdx.x] - x;
    if (threadIdx.x == 511) ptr[N_GRID] = sdata[511];  // total padded count
}

// ---- K2c: add block offsets ----
__global__ __launch_bounds__(512) void scan3_kernel(int* __restrict__ ptr,
                                                    const int* __restrict__ bsums) {
    int i = blockIdx.x * 512 + threadIdx.x;
    ptr[i] = ptr[i] + bsums[blockIdx.x];
}

// ---- K3: [blocks 0..SCAT) scatter entries  ||  [SCAT..SCAT+PADZ) zero pad slots ----
__global__ __launch_bounds__(256) void csr_scatter_kernel(const float* __restrict__ vals,
                                                          const int* __restrict__ rows,
                                                          const int* __restrict__ cols,
                                                          const int* __restrict__ ptr,
                                                          const int* __restrict__ counts,
                                                          const int* __restrict__ rank,
                                                          v2i* __restrict__ pairs) {
    if (blockIdx.x < SCAT_BLOCKS) {
        int k0 = blockIdx.x * 1024 + threadIdx.x;
        int kend = blockIdx.x * 1024 + 1024;
#pragma unroll
        for (int k = k0; k < kend; k += 256) {
            int r = __builtin_nontemporal_load(&rows[k]);
            int c = __builtin_nontemporal_load(&cols[k]);
            float v = __builtin_nontemporal_load(&vals[k]);
            int rk = __builtin_nontemporal_load(&rank[k]);
            int pos = ptr[r] + rk;   // ptr is 1 MB, stays cached
            v2i q; q.x = c; q.y = __float_as_int(v);
            pairs[pos] = q;          // normal store: want pairs L3-resident for K5
        }
    } else {
        int bid = blockIdx.x - SCAT_BLOCKS;
#pragma unroll
        for (int rr = 0; rr < 4; ++rr) {
            int r = bid * 1024 + rr * 256 + threadIdx.x;
            int e = ptr[r] + counts[r];
            int e1 = ptr[r + 1];
            v2i z; z.x = 0; z.y = 0;
            for (; e < e1; ++e) pairs[e] = z;   // <= 8 pad slots per row
        }
    }
}

// 8-wide gather-FMA chunk (tail path)
__device__ __forceinline__ float chunk8(const v2i* __restrict__ pairs, int e,
                                        const float* __restrict__ ypT, int b, float y) {
    v2i q[8];
#pragma unroll
    for (int u = 0; u < 8; ++u) q[u] = pairs[e + u];
    float gv[8];
#pragma unroll
    for (int u = 0; u < 8; ++u) gv[u] = ypT[q[u].x * BSZ + b];
#pragma unroll
    for (int u = 0; u < 8; ++u) y = fmaf(__int_as_float(q[u].y), gv[u], y);
    return y;
}

// ---- K4: fused SpMV + all five per-batch reductions, full batch, one launch ----
__global__ __launch_bounds__(256, 8) void fused_kernel(const float* __restrict__ ypT,
                                                       const float* __restrict__ yt,
                                                       const int* __restrict__ ptr,
                                                       const v2i* __restrict__ pairs,
                                                       float* __restrict__ partial) {
    __shared__ __align__(16) float ytile[ROWS_PER_BLOCK * 129];  // 16512 B, reused as red[]
    int b = threadIdx.x & 127;
    int g = threadIdx.x >> 7;  // 0 or 1
    int n0 = blockIdx.x * ROWS_PER_BLOCK;

    for (int idx = threadIdx.x; idx < ROWS_PER_BLOCK * 128; idx += 256) {
        int bb = idx >> 5;
        int j = idx & 31;
        ytile[j * 129 + bb] = __builtin_nontemporal_load(&yt[(size_t)bb * N_GRID + n0 + j]);
    }
    __syncthreads();

    double a1 = 0.0, at2 = 0.0, a2 = 0.0, a3 = 0.0, a4 = 0.0;
    // group g owns rows {g, g+2, ..., g+30}; process two per iteration
    for (int jj = 0; jj < 8; ++jj) {
        int nlA = g + 4 * jj;
        int nlB = nlA + 2;
        int nA = n0 + nlA;
        int nB = n0 + nlB;
        int eA0 = __builtin_amdgcn_readfirstlane(ptr[nA]);
        int eA1 = __builtin_amdgcn_readfirstlane(ptr[nA + 1]);
        int eB0 = __builtin_amdgcn_readfirstlane(ptr[nB]);
        int eB1 = __builtin_amdgcn_readfirstlane(ptr[nB + 1]);
        float pA = ypT[nA * BSZ + b];
        float pB = ypT[nB * BSZ + b];

        // first chunk of both rows, interleaved (every row has >= 8 padded slots)
        v2i qA[8], qB[8];
#pragma unroll
        for (int u = 0; u < 8; ++u) qA[u] = pairs[eA0 + u];
#pragma unroll
        for (int u = 0; u < 8; ++u) qB[u] = pairs[eB0 + u];
        float gA[8], gB[8];
#pragma unroll
        for (int u = 0; u < 8; ++u) gA[u] = ypT[qA[u].x * BSZ + b];
#pragma unroll
        for (int u = 0; u < 8; ++u) gB[u] = ypT[qB[u].x * BSZ + b];
        float yA = 0.0f, yB = 0.0f;
#pragma unroll
        for (int u = 0; u < 8; ++u) yA = fmaf(__int_as_float(qA[u].y), gA[u], yA);
#pragma unroll
        for (int u = 0; u < 8; ++u) yB = fmaf(__int_as_float(qB[u].y), gB[u], yB);
        // rare tails (rows with > 8 entries)
        for (int e = eA0 + 8; e < eA1; e += 8) yA = chunk8(pairs, e, ypT, b, yA);
        for (int e = eB0 + 8; e < eB1; e += 8) yB = chunk8(pairs, e, ypT, b, yB);

        float tA = ytile[nlA * 129 + b];
        float tB = ytile[nlB * 129 + b];
        a1 += (double)tA * (double)pA;  at2 += (double)tA * (double)tA;
        a2 += (double)pA * (double)yA;  a3 += (double)tA * (double)yA;
        a4 += (double)yA * (double)yA;
        a1 += (double)tB * (double)pB;  at2 += (double)tB * (double)tB;
        a2 += (double)pB * (double)yB;  a3 += (double)tB * (double)yB;
        a4 += (double)yB * (double)yB;
    }

    __syncthreads();                       // ytile reads done; reuse as red[]
    double* red = (double*)ytile;          // 5*128*8 = 5120 B <= 16512 B
    if (g == 1) {
        red[b] = a1; red[BSZ + b] = at2; red[2 * BSZ + b] = a2;
        red[3 * BSZ + b] = a3; red[4 * BSZ + b] = a4;
    }
    __syncthreads();
    if (g == 0) {
        float* pb = partial + (size_t)blockIdx.x * (5 * BSZ);
        __builtin_nontemporal_store((float)(a1 + red[b]), &pb[b]);
        __builtin_nontemporal_store((float)(at2 + red[BSZ + b]), &pb[BSZ + b]);
        __builtin_nontemporal_store((float)(a2 + red[2 * BSZ + b]), &pb[2 * BSZ + b]);
        __builtin_nontemporal_store((float)(a3 + red[3 * BSZ + b]), &pb[3 * BSZ + b]);
        __builtin_nontemporal_store((float)(a4 + red[4 * BSZ + b]), &pb[4 * BSZ + b]);
    }
}

// ---- K5: reduce partials into acc (grid: (5, 16), 128 threads) ----
__global__ __launch_bounds__(128) void reduce2_kernel(const float* __restrict__ partial,
                                                      double* __restrict__ acc) {
    int s = blockIdx.x;
    int chunk = blockIdx.y;
    int b = threadIdx.x;
    const int PER = NBLK_FUSED / 16;  // 512
    double sum = 0.0;
    int i0 = chunk * PER;
#pragma unroll 4
    for (int i = 0; i < PER; ++i) {
        sum += (double)__builtin_nontemporal_load(
            &partial[(size_t)(i0 + i) * (5 * BSZ) + s * BSZ + b]);
    }
    atomicAdd(&acc[s * BSZ + b], sum);
}

// ---- K6: loss_b = t2 - 2*scale*s3 + scale^2*s4; out = mean_b ----
__global__ __launch_bounds__(128) void finalize_kernel(const double* __restrict__ acc,
                                                       float* __restrict__ out) {
    const double* s1 = acc;
    const double* t2 = acc + BSZ;
    const double* s2 = acc + 2 * BSZ;
    const double* s3 = acc + 3 * BSZ;
    const double* s4 = acc + 4 * BSZ;
    int b = threadIdx.x;
    double scale = s1[b] / s2[b];
    double loss = t2[b] - 2.0 * scale * s3[b] + scale * scale * s4[b];
#pragma unroll
    for (int off = 32; off; off >>= 1) loss += __shfl_down(loss, off);
    __shared__ double l[2];
    if ((threadIdx.x & 63) == 0) l[threadIdx.x >> 6] = loss;
    __syncthreads();
    if (threadIdx.x == 0) out[0] = (float)((l[0] + l[1]) / (double)BSZ);
}

extern "C" void kernel_launch(void* const* d_in, const int* in_sizes, int n_in,
                              void* d_out, int out_size, void* d_ws, size_t ws_size,
                              hipStream_t stream) {
    const float* y_pred = (const float*)d_in[0];
    const float* y_true = (const float*)d_in[1];
    const float* vals   = (const float*)d_in[2];
    const int*   rows   = (const int*)d_in[3];
    const int*   cols   = (const int*)d_in[4];
    float* out = (float*)d_out;

    char* ws = (char*)d_ws;
    float*  ypT    = (float*)ws;                         // 134 MB
    double* acc    = (double*)(ws + (size_t)N_GRID * BSZ * 4);
    int*    counts = (int*)((char*)acc + 5 * BSZ * 8);
    int*    ptr    = counts + N_GRID;
    int*    bsums  = ptr + N_GRID + 2;
    v2i*    pairs  = (v2i*)(bsums + 512);                // 31.5 MB
    float*  partial = (float*)(pairs + PAIR_CAP);        // 21 MB
    int*    rank   = (int*)partial;                      // 7.3 MB overlay; dead before fused

    // zero acc + counts (adjacent); pairs pad slots are zeroed inside K3
    hipMemsetAsync(acc, 0, 5 * BSZ * 8 + (size_t)N_GRID * 4, stream);

    phase1_kernel<<<TR_BLOCKS + HIST_BLOCKS, 256, 0, stream>>>(y_pred, ypT, rows, counts, rank);
    scan1_kernel<<<N_GRID / 512, 512, 0, stream>>>(counts, ptr, bsums);
    scan2_kernel<<<1, 512, 0, stream>>>(bsums, ptr);
    scan3_kernel<<<N_GRID / 512, 512, 0, stream>>>(ptr, bsums);
    csr_scatter_kernel<<<SCAT_BLOCKS + PADZ_BLOCKS, 256, 0, stream>>>(vals, rows, cols, ptr,
                                                                      counts, rank, pairs);
    fused_kernel<<<NBLK_FUSED, 256, 0, stream>>>(ypT, y_true, ptr, pairs, partial);
    reduce2_kernel<<<dim3(5, 16), 128, 0, stream>>>(partial, acc);
    finalize_kernel<<<1, 128, 0, stream>>>(acc, out);
}

// Round 6
// 586.836 us; speedup vs baseline: 1.1261x; 1.1261x over previous
//
#include <hip/hip_runtime.h>

#define N_GRID 262144
#define BSZ 128
#define NNZ_TOT 1835008
#define ROWS_PER_BLOCK 32
#define NBLK_FUSED (N_GRID / ROWS_PER_BLOCK)   // 8192
#define PAIR_CAP (NNZ_TOT + 8 * N_GRID)        // min-8 padded worst case = 3932160

typedef float v4f __attribute__((ext_vector_type(4)));
typedef int   v2i __attribute__((ext_vector_type(2)));

// ws layout (8B-aligned):
//   ypT     : N*BSZ f32          = 134 MB  (y_pred transposed)
//   acc     : 5*128 doubles      = 5120 B  (s1, t2, s2, s3, s4)
//   counts  : N ints             = 1 MB
//   ptr     : N+2 ints           = 1 MB    (chunk-local exclusive prefix; global = ptr+bsums)
//   bsums   : 514 ints           = 2 KB    (exclusive chunk offsets; [512]=0 sentinel)
//   pairs   : PAIR_CAP int2      = 31.5 MB (col, bitcast val), row-sorted, zero-padded
//   partial : NBLK_FUSED*640 f32 = 21 MB   (per-block partial sums)
//   rank    : overlays partial   = 7.3 MB  (per-nonzero rank within row; dead before fused)

// ---- K1: histogram of rows + per-entry rank ----
__global__ __launch_bounds__(256) void hist_kernel(const int* __restrict__ rows,
                                                   int* __restrict__ counts,
                                                   int* __restrict__ rank) {
    int k0 = blockIdx.x * 1024 + threadIdx.x;
    int kend = blockIdx.x * 1024 + 1024;
#pragma unroll
    for (int k = k0; k < kend; k += 256) {
        int r = __builtin_nontemporal_load(&rows[k]);
        int rk = atomicAdd(&counts[r], 1);
        __builtin_nontemporal_store(rk, &rank[k]);
    }
}

// ---- K2a: per-block exclusive scan of PADDED counts (512 elems/block) ----
__global__ __launch_bounds__(512) void scan1_kernel(const int* __restrict__ counts,
                                                    int* __restrict__ ptr,
                                                    int* __restrict__ bsums) {
    __shared__ int sdata[512];
    int i = blockIdx.x * 512 + threadIdx.x;
    int x = (counts[i] + 7) & ~7;   // pad each row to a multiple of 8
    if (x < 8) x = 8;               // min 8 slots: first chunk unconditional in fused
    sdata[threadIdx.x] = x;
    __syncthreads();
    for (int off = 1; off < 512; off <<= 1) {
        int v = 0;
        if ((int)threadIdx.x >= off) v = sdata[threadIdx.x - off];
        __syncthreads();
        sdata[threadIdx.x] += v;
        __syncthreads();
    }
    ptr[i] = sdata[threadIdx.x] - x;             // chunk-local exclusive
    if (threadIdx.x == 511) bsums[blockIdx.x] = sdata[511];   // chunk total
}

// ---- K2b: exclusive scan of 512 chunk totals; ptr[N]=grand total; bsums[512]=0 ----
__global__ __launch_bounds__(512) void scan2_kernel(int* __restrict__ bsums,
                                                    int* __restrict__ ptr) {
    __shared__ int sdata[512];
    int x = bsums[threadIdx.x];
    sdata[threadIdx.x] = x;
    __syncthreads();
    for (int off = 1; off < 512; off <<= 1) {
        int v = 0;
        if ((int)threadIdx.x >= off) v = sdata[threadIdx.x - off];
        __syncthreads();
        sdata[threadIdx.x] += v;
        __syncthreads();
    }
    bsums[threadIdx.x] = sdata[threadIdx.x] - x;
    if (threadIdx.x == 511) {
        ptr[N_GRID] = sdata[511];   // total padded count (chunk-local part for row N)
        bsums[512] = 0;             // sentinel so e1 of last row adds 0
    }
}

// ---- K3: scatter (col,val) pairs into padded CSR slots; atomic-free ----
__global__ __launch_bounds__(256) void csr_scatter_kernel(const float* __restrict__ vals,
                                                          const int* __restrict__ rows,
                                                          const int* __restrict__ cols,
                                                          const int* __restrict__ ptr,
                                                          const int* __restrict__ bsums,
                                                          const int* __restrict__ rank,
                                                          v2i* __restrict__ pairs) {
    int k0 = blockIdx.x * 1024 + threadIdx.x;
    int kend = blockIdx.x * 1024 + 1024;
#pragma unroll
    for (int k = k0; k < kend; k += 256) {
        int r = __builtin_nontemporal_load(&rows[k]);
        int c = __builtin_nontemporal_load(&cols[k]);
        float v = __builtin_nontemporal_load(&vals[k]);
        int rk = __builtin_nontemporal_load(&rank[k]);
        int pos = ptr[r] + bsums[r >> 9] + rk;   // ptr/bsums are small, stay cached
        v2i q; q.x = c; q.y = __float_as_int(v);
        pairs[pos] = q;          // normal store: want pairs L3-resident for fused
    }
}

// ---- K4: transpose y_pred (BSZ, N) -> ypT (N, BSZ); runs LAST so ypT is L3-fresh ----
__global__ __launch_bounds__(256) void transpose_kernel(const float* __restrict__ yp,
                                                        float* __restrict__ ypT) {
    __shared__ float tile[64 * 65];
    int n0 = blockIdx.x * 64;
    int b0 = blockIdx.y * 64;
    int tx = threadIdx.x & 15;   // 0..15 -> 4 floats each
    int ty = threadIdx.x >> 4;   // 0..15
#pragma unroll
    for (int jj = 0; jj < 4; ++jj) {
        int b = b0 + ty + jj * 16;
        v4f v = __builtin_nontemporal_load((const v4f*)&yp[(size_t)b * N_GRID + n0 + 4 * tx]);
        tile[(4 * tx + 0) * 65 + ty + jj * 16] = v.x;
        tile[(4 * tx + 1) * 65 + ty + jj * 16] = v.y;
        tile[(4 * tx + 2) * 65 + ty + jj * 16] = v.z;
        tile[(4 * tx + 3) * 65 + ty + jj * 16] = v.w;
    }
    __syncthreads();
#pragma unroll
    for (int jj = 0; jj < 4; ++jj) {
        int nl = ty + jj * 16;
        v4f v;
        v.x = tile[nl * 65 + 4 * tx + 0];
        v.y = tile[nl * 65 + 4 * tx + 1];
        v.z = tile[nl * 65 + 4 * tx + 2];
        v.w = tile[nl * 65 + 4 * tx + 3];
        *(v4f*)&ypT[(size_t)(n0 + nl) * BSZ + b0 + 4 * tx] = v;  // normal: want L3-resident
    }
}

// 8-wide gather-FMA chunk (tail path)
__device__ __forceinline__ float chunk8(const v2i* __restrict__ pairs, int e,
                                        const float* __restrict__ ypT, int b, float y) {
    v2i q[8];
#pragma unroll
    for (int u = 0; u < 8; ++u) q[u] = pairs[e + u];
    float gv[8];
#pragma unroll
    for (int u = 0; u < 8; ++u) gv[u] = ypT[q[u].x * BSZ + b];
#pragma unroll
    for (int u = 0; u < 8; ++u) y = fmaf(__int_as_float(q[u].y), gv[u], y);
    return y;
}

// ---- K5: fused SpMV + all five per-batch reductions, full batch ----
__global__ __launch_bounds__(256, 8) void fused_kernel(const float* __restrict__ ypT,
                                                       const float* __restrict__ yt,
                                                       const int* __restrict__ ptr,
                                                       const int* __restrict__ bsums,
                                                       const v2i* __restrict__ pairs,
                                                       float* __restrict__ partial) {
    __shared__ __align__(16) float ytile[ROWS_PER_BLOCK * 129];  // 16512 B, reused as red[]
    int b = threadIdx.x & 127;
    int g = threadIdx.x >> 7;  // 0 or 1
    int n0 = blockIdx.x * ROWS_PER_BLOCK;

    for (int idx = threadIdx.x; idx < ROWS_PER_BLOCK * 128; idx += 256) {
        int bb = idx >> 5;
        int j = idx & 31;
        ytile[j * 129 + bb] = __builtin_nontemporal_load(&yt[(size_t)bb * N_GRID + n0 + j]);
    }
    __syncthreads();

    double a1 = 0.0, at2 = 0.0, a2 = 0.0, a3 = 0.0, a4 = 0.0;
    // group g owns rows {g, g+2, ..., g+30}; process two per iteration
    for (int jj = 0; jj < 8; ++jj) {
        int nlA = g + 4 * jj;
        int nlB = nlA + 2;
        int nA = n0 + nlA;
        int nB = n0 + nlB;
        int eA0 = __builtin_amdgcn_readfirstlane(ptr[nA] + bsums[nA >> 9]);
        int eA1 = __builtin_amdgcn_readfirstlane(ptr[nA + 1] + bsums[(nA + 1) >> 9]);
        int eB0 = __builtin_amdgcn_readfirstlane(ptr[nB] + bsums[nB >> 9]);
        int eB1 = __builtin_amdgcn_readfirstlane(ptr[nB + 1] + bsums[(nB + 1) >> 9]);
        float pA = ypT[nA * BSZ + b];
        float pB = ypT[nB * BSZ + b];

        // first chunk of both rows, interleaved (every row has >= 8 padded slots)
        v2i qA[8], qB[8];
#pragma unroll
        for (int u = 0; u < 8; ++u) qA[u] = pairs[eA0 + u];
#pragma unroll
        for (int u = 0; u < 8; ++u) qB[u] = pairs[eB0 + u];
        float gA[8], gB[8];
#pragma unroll
        for (int u = 0; u < 8; ++u) gA[u] = ypT[qA[u].x * BSZ + b];
#pragma unroll
        for (int u = 0; u < 8; ++u) gB[u] = ypT[qB[u].x * BSZ + b];
        float yA = 0.0f, yB = 0.0f;
#pragma unroll
        for (int u = 0; u < 8; ++u) yA = fmaf(__int_as_float(qA[u].y), gA[u], yA);
#pragma unroll
        for (int u = 0; u < 8; ++u) yB = fmaf(__int_as_float(qB[u].y), gB[u], yB);
        // rare tails (rows with > 8 entries)
        for (int e = eA0 + 8; e < eA1; e += 8) yA = chunk8(pairs, e, ypT, b, yA);
        for (int e = eB0 + 8; e < eB1; e += 8) yB = chunk8(pairs, e, ypT, b, yB);

        float tA = ytile[nlA * 129 + b];
        float tB = ytile[nlB * 129 + b];
        a1 += (double)tA * (double)pA;  at2 += (double)tA * (double)tA;
        a2 += (double)pA * (double)yA;  a3 += (double)tA * (double)yA;
        a4 += (double)yA * (double)yA;
        a1 += (double)tB * (double)pB;  at2 += (double)tB * (double)tB;
        a2 += (double)pB * (double)yB;  a3 += (double)tB * (double)yB;
        a4 += (double)yB * (double)yB;
    }

    __syncthreads();                       // ytile reads done; reuse as red[]
    double* red = (double*)ytile;          // 5*128*8 = 5120 B <= 16512 B
    if (g == 1) {
        red[b] = a1; red[BSZ + b] = at2; red[2 * BSZ + b] = a2;
        red[3 * BSZ + b] = a3; red[4 * BSZ + b] = a4;
    }
    __syncthreads();
    if (g == 0) {
        float* pb = partial + (size_t)blockIdx.x * (5 * BSZ);
        __builtin_nontemporal_store((float)(a1 + red[b]), &pb[b]);
        __builtin_nontemporal_store((float)(at2 + red[BSZ + b]), &pb[BSZ + b]);
        __builtin_nontemporal_store((float)(a2 + red[2 * BSZ + b]), &pb[2 * BSZ + b]);
        __builtin_nontemporal_store((float)(a3 + red[3 * BSZ + b]), &pb[3 * BSZ + b]);
        __builtin_nontemporal_store((float)(a4 + red[4 * BSZ + b]), &pb[4 * BSZ + b]);
    }
}

// ---- K6: reduce partials into acc (grid: (5, 256), 128 threads; PER=32) ----
__global__ __launch_bounds__(128) void reduce2_kernel(const float* __restrict__ partial,
                                                      double* __restrict__ acc) {
    int s = blockIdx.x;
    int chunk = blockIdx.y;
    int b = threadIdx.x;
    const int PER = NBLK_FUSED / 256;  // 32
    double sum = 0.0;
    int i0 = chunk * PER;
#pragma unroll 8
    for (int i = 0; i < PER; ++i) {
        sum += (double)__builtin_nontemporal_load(
            &partial[(size_t)(i0 + i) * (5 * BSZ) + s * BSZ + b]);
    }
    atomicAdd(&acc[s * BSZ + b], sum);
}

// ---- K7: loss_b = t2 - 2*scale*s3 + scale^2*s4; out = mean_b ----
__global__ __launch_bounds__(128) void finalize_kernel(const double* __restrict__ acc,
                                                       float* __restrict__ out) {
    const double* s1 = acc;
    const double* t2 = acc + BSZ;
    const double* s2 = acc + 2 * BSZ;
    const double* s3 = acc + 3 * BSZ;
    const double* s4 = acc + 4 * BSZ;
    int b = threadIdx.x;
    double scale = s1[b] / s2[b];
    double loss = t2[b] - 2.0 * scale * s3[b] + scale * scale * s4[b];
#pragma unroll
    for (int off = 32; off; off >>= 1) loss += __shfl_down(loss, off);
    __shared__ double l[2];
    if ((threadIdx.x & 63) == 0) l[threadIdx.x >> 6] = loss;
    __syncthreads();
    if (threadIdx.x == 0) out[0] = (float)((l[0] + l[1]) / (double)BSZ);
}

extern "C" void kernel_launch(void* const* d_in, const int* in_sizes, int n_in,
                              void* d_out, int out_size, void* d_ws, size_t ws_size,
                              hipStream_t stream) {
    const float* y_pred = (const float*)d_in[0];
    const float* y_true = (const float*)d_in[1];
    const float* vals   = (const float*)d_in[2];
    const int*   rows   = (const int*)d_in[3];
    const int*   cols   = (const int*)d_in[4];
    float* out = (float*)d_out;

    char* ws = (char*)d_ws;
    float*  ypT    = (float*)ws;                         // 134 MB
    double* acc    = (double*)(ws + (size_t)N_GRID * BSZ * 4);
    int*    counts = (int*)((char*)acc + 5 * BSZ * 8);
    int*    ptr    = counts + N_GRID;
    int*    bsums  = ptr + N_GRID + 2;                   // 514 ints
    v2i*    pairs  = (v2i*)(bsums + 514);                // 31.5 MB
    float*  partial = (float*)(pairs + PAIR_CAP);        // 21 MB
    int*    rank   = (int*)partial;                      // 7.3 MB overlay; dead before fused

    // zero acc + counts (adjacent), and the padded pairs region
    hipMemsetAsync(acc, 0, 5 * BSZ * 8 + (size_t)N_GRID * 4, stream);
    hipMemsetAsync(pairs, 0, (size_t)PAIR_CAP * 8, stream);

    hist_kernel<<<NNZ_TOT / 1024, 256, 0, stream>>>(rows, counts, rank);
    scan1_kernel<<<N_GRID / 512, 512, 0, stream>>>(counts, ptr, bsums);
    scan2_kernel<<<1, 512, 0, stream>>>(bsums, ptr);
    csr_scatter_kernel<<<NNZ_TOT / 1024, 256, 0, stream>>>(vals, rows, cols, ptr, bsums,
                                                           rank, pairs);
    transpose_kernel<<<dim3(N_GRID / 64, BSZ / 64), 256, 0, stream>>>(y_pred, ypT);
    fused_kernel<<<NBLK_FUSED, 256, 0, stream>>>(ypT, y_true, ptr, bsums, pairs, partial);
    reduce2_kernel<<<dim3(5, 256), 128, 0, stream>>>(partial, acc);
    finalize_kernel<<<1, 128, 0, stream>>>(acc, out);
}